// Round 1
// baseline (27.869 us; speedup 1.0000x reference)
//
#include <hip/hip_runtime.h>
#include <math.h>

// Problem constants (from setup_inputs): B=8, P=512, G=128, C=68
#define B_ 8
#define P_ 512
#define G_ 128
#define C_ 68
#define NT 256            // threads per block (kernel 1)
#define PPT (P_ / NT)     // preds per thread = 2
#define BG (B_ * G_)      // 1024 (b,g) pairs

// Kernel 1: one block per (b,g). Each thread computes intersection areas for
// PPT preds (Sutherland-Hodgman, polygon buffers in LDS [point][thread]),
// block reduces to (best area, first argmax index), thread 0 computes the
// CE term + correct flag for this gt and writes to workspace.
__global__ __launch_bounds__(NT) void area_match_kernel(
    const float* __restrict__ bboxes,   // [B,P,9]
    const float* __restrict__ scores,   // [B,P,C]
    const float* __restrict__ polys,    // [B,G,4,2]
    const int*   __restrict__ labels,   // [B,G]
    float* __restrict__ ce_out,         // [BG]
    int*   __restrict__ corr_out)       // [BG]
{
#pragma clang fp contract(off)
    const int bg = blockIdx.x;
    const int b  = bg / G_;
    const int g  = bg % G_;
    const int t  = threadIdx.x;

    __shared__ float s_ax[8 * NT], s_ay[8 * NT];   // poly buffer A
    __shared__ float s_bx[8 * NT], s_by[8 * NT];   // poly buffer B
    __shared__ float sA[NT];
    __shared__ int   sI[NT];

    // ---- clip quad (gt polygon), same for all threads ----
    const float* cp = polys + ((size_t)(b * G_ + g)) * 8;
    const float cx0 = cp[0], cy0 = cp[1], cx1 = cp[2], cy1 = cp[3];
    const float cx2 = cp[4], cy2 = cp[5], cx3 = cp[6], cy3 = cp[7];

    // shoelace signed area as in reference: sum x_i*y_{i+1} - x_{i+1}*y_i
    const float sa = (cx0 * cy1 - cx1 * cy0) + (cx1 * cy2 - cx2 * cy1)
                   + (cx2 * cy3 - cx3 * cy2) + (cx3 * cy0 - cx0 * cy3);
    const bool rev = (sa < 0.0f);

    // clip in CCW order (reverse if sa < 0), compile-time indexed
    const float ccx[4] = { rev ? cx3 : cx0, rev ? cx2 : cx1,
                           rev ? cx1 : cx2, rev ? cx0 : cx3 };
    const float ccy[4] = { rev ? cy3 : cy0, rev ? cy2 : cy1,
                           rev ? cy1 : cy2, rev ? cy0 : cy3 };

    // gt degenerate: any exactly-equal vertex pair (order-invariant)
    const bool gt_deg =
        (cx0 == cx1 && cy0 == cy1) || (cx0 == cx2 && cy0 == cy2) ||
        (cx0 == cx3 && cy0 == cy3) || (cx1 == cx2 && cy1 == cy2) ||
        (cx1 == cx3 && cy1 == cy3) || (cx2 == cx3 && cy2 == cy3);

    float bestA = -1.0f;
    int   bestI = 0;

    for (int r = 0; r < PPT; ++r) {
        const int p = t + r * NT;
        const float* bb = bboxes + ((size_t)(b * P_ + p)) * 9;
        const float sx0 = bb[0], sy0 = bb[1], sx1 = bb[2], sy1 = bb[3];
        const float sx2 = bb[4], sy2 = bb[5], sx3 = bb[6], sy3 = bb[7];

        const bool pdeg =
            (sx0 == sx1 && sy0 == sy1) || (sx0 == sx2 && sy0 == sy2) ||
            (sx0 == sx3 && sy0 == sy3) || (sx1 == sx2 && sy1 == sy2) ||
            (sx1 == sx3 && sy1 == sy3) || (sx2 == sx3 && sy2 == sy3);

        // init subject polygon into buffer A
        s_ax[0 * NT + t] = sx0; s_ay[0 * NT + t] = sy0;
        s_ax[1 * NT + t] = sx1; s_ay[1 * NT + t] = sy1;
        s_ax[2 * NT + t] = sx2; s_ay[2 * NT + t] = sy2;
        s_ax[3 * NT + t] = sx3; s_ay[3 * NT + t] = sy3;
        int n = 4;

        float* curx = s_ax; float* cury = s_ay;
        float* outx = s_bx; float* outy = s_by;

        #pragma unroll
        for (int e = 0; e < 4; ++e) {
            const float eax = ccx[e], eay = ccy[e];
            const float ebx = ccx[(e + 1) & 3], eby = ccy[(e + 1) & 3];
            const float ex = ebx - eax, ey = eby - eay;
            int m = 0;
            for (int i = 0; i < n; ++i) {
                const int j = (i + 1 == n) ? 0 : i + 1;
                const float pxi = curx[i * NT + t], pyi = cury[i * NT + t];
                const float pxj = curx[j * NT + t], pyj = cury[j * NT + t];
                const float dp = ex * (pyi - eay) - ey * (pxi - eax);
                const float dq = ex * (pyj - eay) - ey * (pxj - eax);
                const bool inp = (dp >= 0.0f);
                const bool inq = (dq >= 0.0f);
                if (inp) {
                    if (m < 8) { outx[m * NT + t] = pxi; outy[m * NT + t] = pyi; }
                    ++m;
                }
                if (inp != inq) {
                    const float den = dp - dq;
                    const float tt = (den == 0.0f) ? 0.0f : dp / den;
                    if (m < 8) {
                        outx[m * NT + t] = pxi + tt * (pxj - pxi);
                        outy[m * NT + t] = pyi + tt * (pyj - pyi);
                    }
                    ++m;
                }
            }
            n = (m > 8) ? 8 : m;
            float* tx = curx; curx = outx; outx = tx;
            float* ty = cury; cury = outy; outy = ty;
        }

        float s = 0.0f;
        for (int i = 0; i < n; ++i) {
            const int j = (i + 1 == n) ? 0 : i + 1;
            s += curx[i * NT + t] * cury[j * NT + t]
               - curx[j * NT + t] * cury[i * NT + t];
        }
        float area = fabsf(0.5f * s);
        if (pdeg) area = 0.0f;

        // first-occurrence argmax (r increasing => p increasing, '>' keeps first)
        if (area > bestA) { bestA = area; bestI = p; }
    }

    sA[t] = bestA; sI[t] = bestI;
    __syncthreads();
    for (int gap = NT / 2; gap > 0; gap >>= 1) {
        if (t < gap) {
            const float a2 = sA[t + gap]; const int i2 = sI[t + gap];
            if (a2 > sA[t] || (a2 == sA[t] && i2 < sI[t])) { sA[t] = a2; sI[t] = i2; }
        }
        __syncthreads();
    }

    if (t == 0) {
        const float best = sA[0];
        const int gmax = sI[0];
        const bool matched = (!gt_deg) && (best != 0.0f);
        const int label = labels[b * G_ + g];
        float ce;
        int corr;
        if (matched) {
            const float* sc = scores + ((size_t)(b * P_ + gmax)) * C_;
            float mx = sc[0]; int am = 0;
            for (int c = 1; c < C_; ++c) {
                const float v = sc[c];
                if (v > mx) { mx = v; am = c; }
            }
            float sum = 0.0f;
            for (int c = 0; c < C_; ++c) sum += expf(sc[c] - mx);
            const float lse = mx + logf(sum);
            ce = lse - sc[label];
            corr = (am == label) ? 1 : 0;
        } else {
            ce = logf((float)C_);  // log-softmax of all-zero row at any class
            corr = 0;              // pred_num = -1 never equals label in [0,C)
        }
        ce_out[bg] = ce;
        corr_out[bg] = corr;
    }
}

// Kernel 2: deterministic tree reduction of the 1024 (ce, corr) pairs.
__global__ __launch_bounds__(1024) void finalize_kernel(
    const float* __restrict__ ce,   // [BG]
    const int*   __restrict__ corr, // [BG]
    float* __restrict__ out)        // [3]
{
    __shared__ float sc[BG];
    __shared__ int   si[BG];
    const int t = threadIdx.x;
    sc[t] = ce[t];
    si[t] = corr[t];
    __syncthreads();
    for (int gap = BG / 2; gap > 0; gap >>= 1) {
        if (t < gap) {
            sc[t] += sc[t + gap];
            si[t] += si[t + gap];
        }
        __syncthreads();
    }
    if (t == 0) {
        out[0] = sc[0] / (float)BG;   // mean_b mean_g ce
        out[1] = (float)BG;           // total_number = B*G
        out[2] = (float)si[0];        // rec_correct
    }
}

extern "C" void kernel_launch(void* const* d_in, const int* in_sizes, int n_in,
                              void* d_out, int out_size, void* d_ws, size_t ws_size,
                              hipStream_t stream) {
    const float* bboxes = (const float*)d_in[0];   // [B,P,9]
    const float* scores = (const float*)d_in[1];   // [B,P,C]
    const float* polys  = (const float*)d_in[2];   // [B,G,4,2]
    const int*   labels = (const int*)d_in[3];     // [B,G]
    float* out = (float*)d_out;

    float* ws_ce   = (float*)d_ws;                 // [BG] floats
    int*   ws_corr = (int*)((char*)d_ws + BG * sizeof(float)); // [BG] ints

    area_match_kernel<<<BG, NT, 0, stream>>>(bboxes, scores, polys, labels,
                                             ws_ce, ws_corr);
    finalize_kernel<<<1, BG, 0, stream>>>(ws_ce, ws_corr, out);
}

// Round 2
// 21.417 us; speedup vs baseline: 1.3012x; 1.3012x over previous
//
#include <hip/hip_runtime.h>
#include <math.h>

// Problem constants: B=8, P=512, G=128, C=68
#define B_ 8
#define P_ 512
#define G_ 128
#define C_ 68
#define BG (B_ * G_)   // 1024
#define BP (B_ * P_)   // 4096
#define NT 256
#define EPS_ 1.0f      // AABB slack: excluded pairs have >=1px gap -> exact 0 in ref

// workspace layout (bytes)
#define OFF_PAABB  0                        // float4 predAABB[BP]   (64KB)
#define OFF_GVERT  (BP * 16)                // float  gtVert[BG][8]  (32KB)
#define OFF_GAABB  (OFF_GVERT + BG * 32)    // float4 gtAABB[BG]     (16KB)
#define OFF_GDEG   (OFF_GAABB + BG * 16)    // int    gtDeg[BG]      (4KB)
#define OFF_CE     (OFF_GDEG + BG * 4)      // float  ce[BG]         (4KB)
#define OFF_CORR   (OFF_CE + BG * 4)        // int    corr[BG]       (4KB)

// Kernel A: per-pred AABB (+degenerate fold) and per-gt CCW verts/AABB/deg.
__global__ __launch_bounds__(NT) void prep_kernel(
    const float* __restrict__ bboxes,   // [BP,9]
    const float* __restrict__ polys,    // [BG,4,2]
    float4* __restrict__ pA,
    float*  __restrict__ gV,
    float4* __restrict__ gA,
    int*    __restrict__ gD)
{
#pragma clang fp contract(off)
    const int i = blockIdx.x * NT + threadIdx.x;
    if (i < BP) {
        const float* bb = bboxes + (size_t)i * 9;
        const float x0 = bb[0], y0 = bb[1], x1 = bb[2], y1 = bb[3];
        const float x2 = bb[4], y2 = bb[5], x3 = bb[6], y3 = bb[7];
        const bool deg =
            (x0 == x1 && y0 == y1) || (x0 == x2 && y0 == y2) ||
            (x0 == x3 && y0 == y3) || (x1 == x2 && y1 == y2) ||
            (x1 == x3 && y1 == y3) || (x2 == x3 && y2 == y3);
        float mnx = fminf(fminf(x0, x1), fminf(x2, x3));
        float mny = fminf(fminf(y0, y1), fminf(y2, y3));
        float mxx = fmaxf(fmaxf(x0, x1), fmaxf(x2, x3));
        float mxy = fmaxf(fmaxf(y0, y1), fmaxf(y2, y3));
        if (deg) { mnx = 3e38f; mny = 3e38f; mxx = -3e38f; mxy = -3e38f; }
        pA[i] = make_float4(mnx, mny, mxx, mxy);
    } else if (i < BP + BG) {
        const int j = i - BP;
        const float* cp = polys + (size_t)j * 8;
        const float x0 = cp[0], y0 = cp[1], x1 = cp[2], y1 = cp[3];
        const float x2 = cp[4], y2 = cp[5], x3 = cp[6], y3 = cp[7];
        const float sa = (x0 * y1 - x1 * y0) + (x1 * y2 - x2 * y1)
                       + (x2 * y3 - x3 * y2) + (x3 * y0 - x0 * y3);
        const bool rev = (sa < 0.0f);
        float* v = gV + (size_t)j * 8;
        v[0] = rev ? x3 : x0; v[1] = rev ? y3 : y0;
        v[2] = rev ? x2 : x1; v[3] = rev ? y2 : y1;
        v[4] = rev ? x1 : x2; v[5] = rev ? y1 : y2;
        v[6] = rev ? x0 : x3; v[7] = rev ? y0 : y3;
        gA[j] = make_float4(fminf(fminf(x0, x1), fminf(x2, x3)),
                            fminf(fminf(y0, y1), fminf(y2, y3)),
                            fmaxf(fmaxf(x0, x1), fmaxf(x2, x3)),
                            fmaxf(fmaxf(y0, y1), fmaxf(y2, y3)));
        const bool deg =
            (x0 == x1 && y0 == y1) || (x0 == x2 && y0 == y2) ||
            (x0 == x3 && y0 == y3) || (x1 == x2 && y1 == y2) ||
            (x1 == x3 && y1 == y3) || (x2 == x3 && y2 == y3);
        gD[j] = deg ? 1 : 0;
    }
}

// Kernel B: one block per (b,g). AABB scan -> survivor list -> wave0 clips
// survivors -> shuffle argmax -> wave-parallel log-softmax CE.
__global__ __launch_bounds__(NT) void match_kernel(
    const float* __restrict__ bboxes,   // [BP,9]
    const float* __restrict__ scores,   // [BP,C]
    const int*   __restrict__ labels,   // [BG]
    const float4* __restrict__ pA,
    const float*  __restrict__ gV,
    const float4* __restrict__ gA,
    const int*    __restrict__ gD,
    float* __restrict__ ce_out,
    int*   __restrict__ corr_out)
{
#pragma clang fp contract(off)
    const int bg = blockIdx.x;
    const int b  = bg / G_;
    const int t  = threadIdx.x;

    __shared__ int   s_n;
    __shared__ int   s_idx[P_];
    __shared__ float s_px[8 * 64], s_py[8 * 64];
    __shared__ float s_qx[8 * 64], s_qy[8 * 64];

    if (t == 0) s_n = 0;
    __syncthreads();

    const float4 gbb = gA[bg];
    #pragma unroll
    for (int r = 0; r < P_ / NT; ++r) {
        const int p = t + r * NT;
        const float4 pb = pA[b * P_ + p];
        const bool ov = (pb.x <= gbb.z + EPS_) && (gbb.x <= pb.z + EPS_) &&
                        (pb.y <= gbb.w + EPS_) && (gbb.y <= pb.w + EPS_);
        if (ov) {
            const int s = atomicAdd(&s_n, 1);
            s_idx[s] = p;
        }
    }
    __syncthreads();

    if (t >= 64) return;   // wave 0 only from here; no further barriers

    const int ns = s_n;

    // clip quad (CCW), registers via compile-time indexing
    const float* cv = gV + (size_t)bg * 8;
    float ccx[4], ccy[4];
    ccx[0] = cv[0]; ccy[0] = cv[1];
    ccx[1] = cv[2]; ccy[1] = cv[3];
    ccx[2] = cv[4]; ccy[2] = cv[5];
    ccx[3] = cv[6]; ccy[3] = cv[7];

    float bestA = 0.0f;
    int   bestI = 0x7fffffff;

    for (int k0 = 0; k0 < ns; k0 += 64) {
        const int k = k0 + t;
        if (k < ns) {
            const int p = s_idx[k];
            const float* bb = bboxes + (size_t)(b * P_ + p) * 9;
            s_px[0 * 64 + t] = bb[0]; s_py[0 * 64 + t] = bb[1];
            s_px[1 * 64 + t] = bb[2]; s_py[1 * 64 + t] = bb[3];
            s_px[2 * 64 + t] = bb[4]; s_py[2 * 64 + t] = bb[5];
            s_px[3 * 64 + t] = bb[6]; s_py[3 * 64 + t] = bb[7];
            int n = 4;
            float* curx = s_px; float* cury = s_py;
            float* outx = s_qx; float* outy = s_qy;
            #pragma unroll
            for (int e = 0; e < 4; ++e) {
                const float eax = ccx[e], eay = ccy[e];
                const float ex = ccx[(e + 1) & 3] - eax;
                const float ey = ccy[(e + 1) & 3] - eay;
                int m = 0;
                for (int i = 0; i < n; ++i) {
                    const int j = (i + 1 == n) ? 0 : i + 1;
                    const float pxi = curx[i * 64 + t], pyi = cury[i * 64 + t];
                    const float pxj = curx[j * 64 + t], pyj = cury[j * 64 + t];
                    const float dp = ex * (pyi - eay) - ey * (pxi - eax);
                    const float dq = ex * (pyj - eay) - ey * (pxj - eax);
                    const bool inp = (dp >= 0.0f);
                    const bool inq = (dq >= 0.0f);
                    if (inp) {
                        if (m < 8) { outx[m * 64 + t] = pxi; outy[m * 64 + t] = pyi; }
                        ++m;
                    }
                    if (inp != inq) {
                        const float den = dp - dq;
                        const float tt = (den == 0.0f) ? 0.0f : dp / den;
                        if (m < 8) {
                            outx[m * 64 + t] = pxi + tt * (pxj - pxi);
                            outy[m * 64 + t] = pyi + tt * (pyj - pyi);
                        }
                        ++m;
                    }
                }
                n = (m > 8) ? 8 : m;
                float* tx = curx; curx = outx; outx = tx;
                float* ty = cury; cury = outy; outy = ty;
            }
            float s = 0.0f;
            for (int i = 0; i < n; ++i) {
                const int j = (i + 1 == n) ? 0 : i + 1;
                s += curx[i * 64 + t] * cury[j * 64 + t]
                   - curx[j * 64 + t] * cury[i * 64 + t];
            }
            const float area = fabsf(0.5f * s);
            if (area > bestA || (area == bestA && p < bestI)) {
                bestA = area; bestI = p;
            }
        }
    }

    // 64-lane (area, min-idx) reduce — order-independent, deterministic
    #pragma unroll
    for (int off = 32; off; off >>= 1) {
        const float oa = __shfl_xor(bestA, off);
        const int   oi = __shfl_xor(bestI, off);
        if (oa > bestA || (oa == bestA && oi < bestI)) { bestA = oa; bestI = oi; }
    }

    const bool matched = (gD[bg] == 0) && (bestA != 0.0f);
    const int label = labels[bg];

    if (matched) {
        const float* sc = scores + (size_t)(b * P_ + bestI) * C_;
        const float v0 = sc[t];
        const bool  h2 = (t + 64) < C_;
        const float v1 = h2 ? sc[t + 64] : -3e38f;
        float bv; int bi;
        if (v1 > v0) { bv = v1; bi = t + 64; } else { bv = v0; bi = t; }
        float mx = fmaxf(v0, v1);
        #pragma unroll
        for (int off = 32; off; off >>= 1) mx = fmaxf(mx, __shfl_xor(mx, off));
        #pragma unroll
        for (int off = 32; off; off >>= 1) {
            const float ov2 = __shfl_xor(bv, off);
            const int   oi2 = __shfl_xor(bi, off);
            if (ov2 > bv || (ov2 == bv && oi2 < bi)) { bv = ov2; bi = oi2; }
        }
        float e = expf(v0 - mx) + (h2 ? expf(v1 - mx) : 0.0f);
        #pragma unroll
        for (int off = 32; off; off >>= 1) e += __shfl_xor(e, off);
        if (t == 0) {
            ce_out[bg]   = mx + logf(e) - sc[label];
            corr_out[bg] = (bi == label) ? 1 : 0;
        }
    } else {
        if (t == 0) {
            ce_out[bg]   = logf((float)C_);
            corr_out[bg] = 0;
        }
    }
}

// Kernel C: deterministic tree reduction of the 1024 (ce, corr) pairs.
__global__ __launch_bounds__(1024) void finalize_kernel(
    const float* __restrict__ ce,
    const int*   __restrict__ corr,
    float* __restrict__ out)
{
    __shared__ float sc[BG];
    __shared__ int   si[BG];
    const int t = threadIdx.x;
    sc[t] = ce[t];
    si[t] = corr[t];
    __syncthreads();
    for (int gap = BG / 2; gap > 0; gap >>= 1) {
        if (t < gap) {
            sc[t] += sc[t + gap];
            si[t] += si[t + gap];
        }
        __syncthreads();
    }
    if (t == 0) {
        out[0] = sc[0] / (float)BG;
        out[1] = (float)BG;
        out[2] = (float)si[0];
    }
}

extern "C" void kernel_launch(void* const* d_in, const int* in_sizes, int n_in,
                              void* d_out, int out_size, void* d_ws, size_t ws_size,
                              hipStream_t stream) {
    const float* bboxes = (const float*)d_in[0];   // [B,P,9]
    const float* scores = (const float*)d_in[1];   // [B,P,C]
    const float* polys  = (const float*)d_in[2];   // [B,G,4,2]
    const int*   labels = (const int*)d_in[3];     // [B,G]
    float* out = (float*)d_out;

    char* ws = (char*)d_ws;
    float4* pA = (float4*)(ws + OFF_PAABB);
    float*  gV = (float*)(ws + OFF_GVERT);
    float4* gA = (float4*)(ws + OFF_GAABB);
    int*    gD = (int*)(ws + OFF_GDEG);
    float*  ce = (float*)(ws + OFF_CE);
    int*    cr = (int*)(ws + OFF_CORR);

    const int prep_blocks = (BP + BG + NT - 1) / NT;
    prep_kernel<<<prep_blocks, NT, 0, stream>>>(bboxes, polys, pA, gV, gA, gD);
    match_kernel<<<BG, NT, 0, stream>>>(bboxes, scores, labels,
                                        pA, gV, gA, gD, ce, cr);
    finalize_kernel<<<1, BG, 0, stream>>>(ce, cr, out);
}

// Round 3
// 17.880 us; speedup vs baseline: 1.5586x; 1.1978x over previous
//
#include <hip/hip_runtime.h>
#include <math.h>

// Problem constants: B=8, P=512, G=128, C=68
#define B_ 8
#define P_ 512
#define G_ 128
#define C_ 68
#define BG (B_ * G_)   // 1024
#define BP (B_ * P_)   // 4096
#define EPS_ 1.0f      // AABB slack: excluded pairs have >1px gap -> exact 0 in ref

// Fused kernel: one 64-thread block (1 wave) per (b,g).
//  - gt prep (CCW order, degenerate test, AABB) in registers, redundantly per lane
//  - 8 preds/lane AABB scan with inline pred-AABB + degenerate fold
//  - ballot+mbcnt compaction into LDS survivor list (deterministic order)
//  - survivors clipped (Sutherland-Hodgman, LDS [pt][64] stride, conflict-free)
//  - wave shuffle (area, min-idx) argmax reduce
//  - wave-parallel 68-wide log-softmax CE
__global__ __launch_bounds__(64) void match_kernel(
    const float* __restrict__ bboxes,   // [BP,9]
    const float* __restrict__ scores,   // [BP,C]
    const float* __restrict__ polys,    // [BG,4,2]
    const int*   __restrict__ labels,   // [BG]
    float* __restrict__ ce_out,         // [BG]
    int*   __restrict__ corr_out)       // [BG]
{
#pragma clang fp contract(off)
    const int bg = blockIdx.x;
    const int b  = bg >> 7;            // / G_
    const int t  = threadIdx.x;

    __shared__ int   s_idx[P_];
    __shared__ float s_px[8 * 64], s_py[8 * 64];
    __shared__ float s_qx[8 * 64], s_qy[8 * 64];

    // ---- gt prep (same expressions as validated round-2 prep) ----
    const float* cp = polys + (size_t)bg * 8;
    const float x0 = cp[0], y0 = cp[1], x1 = cp[2], y1 = cp[3];
    const float x2 = cp[4], y2 = cp[5], x3 = cp[6], y3 = cp[7];
    const float sa = (x0 * y1 - x1 * y0) + (x1 * y2 - x2 * y1)
                   + (x2 * y3 - x3 * y2) + (x3 * y0 - x0 * y3);
    const bool rev = (sa < 0.0f);
    float ccx[4], ccy[4];
    ccx[0] = rev ? x3 : x0; ccy[0] = rev ? y3 : y0;
    ccx[1] = rev ? x2 : x1; ccy[1] = rev ? y2 : y1;
    ccx[2] = rev ? x1 : x2; ccy[2] = rev ? y1 : y2;
    ccx[3] = rev ? x0 : x3; ccy[3] = rev ? y0 : y3;
    const bool gt_deg =
        (x0 == x1 && y0 == y1) || (x0 == x2 && y0 == y2) ||
        (x0 == x3 && y0 == y3) || (x1 == x2 && y1 == y2) ||
        (x1 == x3 && y1 == y3) || (x2 == x3 && y2 == y3);
    const float glox = fminf(fminf(x0, x1), fminf(x2, x3)) - EPS_;
    const float gloy = fminf(fminf(y0, y1), fminf(y2, y3)) - EPS_;
    const float ghix = fmaxf(fmaxf(x0, x1), fmaxf(x2, x3)) + EPS_;
    const float ghiy = fmaxf(fmaxf(y0, y1), fmaxf(y2, y3)) + EPS_;

    // ---- AABB scan: 8 preds per lane, ballot-prefix compaction ----
    const float* bbb = bboxes + (size_t)b * P_ * 9;
    int base = 0;
    #pragma unroll
    for (int r = 0; r < 8; ++r) {
        const int p = t + (r << 6);
        const float* bb = bbb + (size_t)p * 9;
        const float a0 = bb[0], a1 = bb[1], a2 = bb[2], a3 = bb[3];
        const float a4 = bb[4], a5 = bb[5], a6 = bb[6], a7 = bb[7];
        const bool deg =
            (a0 == a2 && a1 == a3) || (a0 == a4 && a1 == a5) ||
            (a0 == a6 && a1 == a7) || (a2 == a4 && a3 == a5) ||
            (a2 == a6 && a3 == a7) || (a4 == a6 && a5 == a7);
        const float lox = fminf(fminf(a0, a2), fminf(a4, a6));
        const float loy = fminf(fminf(a1, a3), fminf(a5, a7));
        const float hix = fmaxf(fmaxf(a0, a2), fmaxf(a4, a6));
        const float hiy = fmaxf(fmaxf(a1, a3), fmaxf(a5, a7));
        const bool ov = !deg &&
            (lox <= ghix) && (glox <= hix) &&
            (loy <= ghiy) && (gloy <= hiy);
        const unsigned long long mask = __ballot(ov);
        if (ov) {
            const int pre = __builtin_amdgcn_mbcnt_hi(
                (unsigned int)(mask >> 32),
                __builtin_amdgcn_mbcnt_lo((unsigned int)mask, 0u));
            s_idx[base + pre] = p;
        }
        base += __popcll(mask);
    }
    const int ns = base;

    // ---- clip survivors (bit-identical SH to validated round 2) ----
    float bestA = 0.0f;
    int   bestI = 0x7fffffff;

    for (int k0 = 0; k0 < ns; k0 += 64) {
        const int k = k0 + t;
        if (k < ns) {
            const int p = s_idx[k];
            const float* bb = bbb + (size_t)p * 9;
            s_px[0 * 64 + t] = bb[0]; s_py[0 * 64 + t] = bb[1];
            s_px[1 * 64 + t] = bb[2]; s_py[1 * 64 + t] = bb[3];
            s_px[2 * 64 + t] = bb[4]; s_py[2 * 64 + t] = bb[5];
            s_px[3 * 64 + t] = bb[6]; s_py[3 * 64 + t] = bb[7];
            int n = 4;
            float* curx = s_px; float* cury = s_py;
            float* outx = s_qx; float* outy = s_qy;
            #pragma unroll
            for (int e = 0; e < 4; ++e) {
                const float eax = ccx[e], eay = ccy[e];
                const float ex = ccx[(e + 1) & 3] - eax;
                const float ey = ccy[(e + 1) & 3] - eay;
                int m = 0;
                for (int i = 0; i < n; ++i) {
                    const int j = (i + 1 == n) ? 0 : i + 1;
                    const float pxi = curx[i * 64 + t], pyi = cury[i * 64 + t];
                    const float pxj = curx[j * 64 + t], pyj = cury[j * 64 + t];
                    const float dp = ex * (pyi - eay) - ey * (pxi - eax);
                    const float dq = ex * (pyj - eay) - ey * (pxj - eax);
                    const bool inp = (dp >= 0.0f);
                    const bool inq = (dq >= 0.0f);
                    if (inp) {
                        if (m < 8) { outx[m * 64 + t] = pxi; outy[m * 64 + t] = pyi; }
                        ++m;
                    }
                    if (inp != inq) {
                        const float den = dp - dq;
                        const float tt = (den == 0.0f) ? 0.0f : dp / den;
                        if (m < 8) {
                            outx[m * 64 + t] = pxi + tt * (pxj - pxi);
                            outy[m * 64 + t] = pyi + tt * (pyj - pyi);
                        }
                        ++m;
                    }
                }
                n = (m > 8) ? 8 : m;
                float* tx = curx; curx = outx; outx = tx;
                float* ty = cury; cury = outy; outy = ty;
            }
            float s = 0.0f;
            for (int i = 0; i < n; ++i) {
                const int j = (i + 1 == n) ? 0 : i + 1;
                s += curx[i * 64 + t] * cury[j * 64 + t]
                   - curx[j * 64 + t] * cury[i * 64 + t];
            }
            const float area = fabsf(0.5f * s);
            if (area > bestA || (area == bestA && p < bestI)) {
                bestA = area; bestI = p;
            }
        }
    }

    // 64-lane (area, min-idx) reduce — order-independent, deterministic
    #pragma unroll
    for (int off = 32; off; off >>= 1) {
        const float oa = __shfl_xor(bestA, off);
        const int   oi = __shfl_xor(bestI, off);
        if (oa > bestA || (oa == bestA && oi < bestI)) { bestA = oa; bestI = oi; }
    }

    const bool matched = (!gt_deg) && (bestA != 0.0f);
    const int label = labels[bg];

    if (matched) {
        const float* sc = scores + (size_t)(b * P_ + bestI) * C_;
        const float v0 = sc[t];
        const bool  h2 = (t + 64) < C_;
        const float v1 = h2 ? sc[t + 64] : -3e38f;
        float bv; int bi;
        if (v1 > v0) { bv = v1; bi = t + 64; } else { bv = v0; bi = t; }
        float mx = fmaxf(v0, v1);
        #pragma unroll
        for (int off = 32; off; off >>= 1) mx = fmaxf(mx, __shfl_xor(mx, off));
        #pragma unroll
        for (int off = 32; off; off >>= 1) {
            const float ov2 = __shfl_xor(bv, off);
            const int   oi2 = __shfl_xor(bi, off);
            if (ov2 > bv || (ov2 == bv && oi2 < bi)) { bv = ov2; bi = oi2; }
        }
        float e = expf(v0 - mx) + (h2 ? expf(v1 - mx) : 0.0f);
        #pragma unroll
        for (int off = 32; off; off >>= 1) e += __shfl_xor(e, off);
        if (t == 0) {
            ce_out[bg]   = mx + logf(e) - sc[label];
            corr_out[bg] = (bi == label) ? 1 : 0;
        }
    } else {
        if (t == 0) {
            ce_out[bg]   = logf((float)C_);
            corr_out[bg] = 0;
        }
    }
}

// Finalize: deterministic fixed-tree reduction of 1024 (ce, corr) pairs.
__global__ __launch_bounds__(256) void finalize_kernel(
    const float* __restrict__ ce,
    const int*   __restrict__ corr,
    float* __restrict__ out)
{
    const int t = threadIdx.x;
    float a = ce[t] + ce[t + 256] + ce[t + 512] + ce[t + 768];
    int   c = corr[t] + corr[t + 256] + corr[t + 512] + corr[t + 768];
    #pragma unroll
    for (int off = 32; off; off >>= 1) {
        a += __shfl_xor(a, off);
        c += __shfl_xor(c, off);
    }
    __shared__ float pa[4];
    __shared__ int   pc[4];
    if ((t & 63) == 0) { pa[t >> 6] = a; pc[t >> 6] = c; }
    __syncthreads();
    if (t == 0) {
        const float s = (pa[0] + pa[1]) + (pa[2] + pa[3]);
        const int  cc = (pc[0] + pc[1]) + (pc[2] + pc[3]);
        out[0] = s / (float)BG;   // mean ce
        out[1] = (float)BG;       // total_number
        out[2] = (float)cc;       // rec_correct
    }
}

extern "C" void kernel_launch(void* const* d_in, const int* in_sizes, int n_in,
                              void* d_out, int out_size, void* d_ws, size_t ws_size,
                              hipStream_t stream) {
    const float* bboxes = (const float*)d_in[0];   // [B,P,9]
    const float* scores = (const float*)d_in[1];   // [B,P,C]
    const float* polys  = (const float*)d_in[2];   // [B,G,4,2]
    const int*   labels = (const int*)d_in[3];     // [B,G]
    float* out = (float*)d_out;

    float* ce = (float*)d_ws;                          // [BG]
    int*   cr = (int*)((char*)d_ws + BG * sizeof(float)); // [BG]

    match_kernel<<<BG, 64, 0, stream>>>(bboxes, scores, polys, labels, ce, cr);
    finalize_kernel<<<1, 256, 0, stream>>>(ce, cr, out);
}